// Round 5
// baseline (37.400 us; speedup 1.0000x reference)
//
#include <hip/hip_runtime.h>
#include <hip/hip_bf16.h>

#define NB 64
#define LQ 32
#define LD 256
#define DD 128
#define NWAY 8
#define NBLOCKS (NB * NWAY)   // 512

typedef __attribute__((ext_vector_type(8))) short short8;
typedef __attribute__((ext_vector_type(4))) float f32x4;

static __device__ __forceinline__ unsigned short f2bf(float f) {
    unsigned int u = __float_as_uint(f);
    u += 0x7fffu + ((u >> 16) & 1u);   // round-to-nearest-even
    return (unsigned short)(u >> 16);
}
static __device__ __forceinline__ unsigned int pk2(float a, float b) {
    return (unsigned int)f2bf(a) | ((unsigned int)f2bf(b) << 16);
}

union bfr { unsigned u[4]; short8 v; };

// One block per (b,n): b=bid&63, n=bid>>6 (blocks sharing b -> same XCD L2).
// 256 threads = 4 waves; wave w owns doc rows [t*64 + w*16, +16) per tile t.
// B-fragments loaded DIRECTLY global->regs (lane l&15 = doc row, lane>>4 = k-pack):
// no LDS, no barriers in the doc loop. Doc rows unnormalized bf16; 1/||d||
// applied post-MFMA (max commutes with positive scales). Masked rows never
// loaded (zeros), gated out of the max. Loss fused into the last-arriving block.
__global__ __launch_bounds__(256, 4) void colbert_fused_kernel(
    const float* __restrict__ qreps,   // [B][LQ][DD]
    const float* __restrict__ dreps,   // [B][NWAY][LD][DD]
    const int*   __restrict__ masks,   // [B][NWAY][LD]
    const float* __restrict__ labels,  // [B][2*NWAY]
    float*       __restrict__ scores,  // ws: [512]
    unsigned*    __restrict__ cnt,     // ws: completion counter (memset 0 each call)
    float*       __restrict__ out)
{
    const int bid  = blockIdx.x;
    const int b    = bid & 63;
    const int n    = bid >> 6;
    const int bn   = b * NWAY + n;
    const int tid  = threadIdx.x;
    const int lane = tid & 63;
    const int w    = tid >> 6;         // 0..3
    const int fr   = lane & 15;        // fragment row/col index
    const int fp   = lane >> 4;        // k-pack 0..3

    __shared__ float qmaxw[4][LQ];
    __shared__ unsigned islast;

    // ---- per-lane masks for my doc row in each of the 4 tiles (issued first) ----
    int mymask[4];
    #pragma unroll
    for (int t = 0; t < 4; ++t)
        mymask[t] = masks[(size_t)bn * LD + t * 64 + w * 16 + fr];

    // ---- Q -> normalized bf16 A-fragments in registers (per-wave, L2-served) ----
    bfr afrag[2][4];
    #pragma unroll
    for (int qh = 0; qh < 2; ++qh) {
        const float* qsrc = qreps + ((size_t)b * LQ + qh * 16 + fr) * DD + fp * 8;
        float qv[32];
        float ss = 0.f;
        #pragma unroll
        for (int kc = 0; kc < 4; ++kc) {
            float4 f0 = reinterpret_cast<const float4*>(qsrc + kc * 32)[0];
            float4 f1 = reinterpret_cast<const float4*>(qsrc + kc * 32)[1];
            qv[kc*8+0]=f0.x; qv[kc*8+1]=f0.y; qv[kc*8+2]=f0.z; qv[kc*8+3]=f0.w;
            qv[kc*8+4]=f1.x; qv[kc*8+5]=f1.y; qv[kc*8+6]=f1.z; qv[kc*8+7]=f1.w;
            ss += f0.x*f0.x+f0.y*f0.y+f0.z*f0.z+f0.w*f0.w
                + f1.x*f1.x+f1.y*f1.y+f1.z*f1.z+f1.w*f1.w;
        }
        ss += __shfl_xor(ss, 16);      // lanes sharing a q row: fr, fr+16, fr+32, fr+48
        ss += __shfl_xor(ss, 32);
        const float rn = rsqrtf(fmaxf(ss, 1e-24f));
        #pragma unroll
        for (int kc = 0; kc < 4; ++kc) {
            afrag[qh][kc].u[0] = pk2(qv[kc*8+0]*rn, qv[kc*8+1]*rn);
            afrag[qh][kc].u[1] = pk2(qv[kc*8+2]*rn, qv[kc*8+3]*rn);
            afrag[qh][kc].u[2] = pk2(qv[kc*8+4]*rn, qv[kc*8+5]*rn);
            afrag[qh][kc].u[3] = pk2(qv[kc*8+6]*rn, qv[kc*8+7]*rn);
        }
    }

    float rmax[2][4];
    #pragma unroll
    for (int qh = 0; qh < 2; ++qh)
        #pragma unroll
        for (int r = 0; r < 4; ++r) rmax[qh][r] = -1e30f;

    // ---- doc tiles: global -> packed bf16 regs, no LDS/barriers ----
    unsigned dpa[16], dpb[16];
    float rnda, rndb;

    auto loadpack = [&](int t, unsigned (&dp)[16], float& rnd) {
        float ss = 0.f;
        if (mymask[t]) {
            const float* src = dreps + ((size_t)bn * LD + t * 64 + w * 16 + fr) * DD + fp * 8;
            #pragma unroll
            for (int kc = 0; kc < 4; ++kc) {
                float4 f0 = reinterpret_cast<const float4*>(src + kc * 32)[0];
                float4 f1 = reinterpret_cast<const float4*>(src + kc * 32)[1];
                ss += f0.x*f0.x+f0.y*f0.y+f0.z*f0.z+f0.w*f0.w
                    + f1.x*f1.x+f1.y*f1.y+f1.z*f1.z+f1.w*f1.w;
                dp[kc*4+0] = pk2(f0.x, f0.y);
                dp[kc*4+1] = pk2(f0.z, f0.w);
                dp[kc*4+2] = pk2(f1.x, f1.y);
                dp[kc*4+3] = pk2(f1.z, f1.w);
            }
        } else {
            #pragma unroll
            for (int i = 0; i < 16; ++i) dp[i] = 0u;
        }
        // all 4 lanes of a row have the same mask -> convergent reduce is valid
        ss += __shfl_xor(ss, 16);
        ss += __shfl_xor(ss, 32);
        rnd = rsqrtf(fmaxf(ss, 1e-24f));
    };

    auto dotile = [&](int t, unsigned (&dp)[16], float rnd) {
        f32x4 acc0 = {0.f, 0.f, 0.f, 0.f};
        f32x4 acc1 = {0.f, 0.f, 0.f, 0.f};
        #pragma unroll
        for (int kc = 0; kc < 4; ++kc) {
            bfr bb;
            bb.u[0] = dp[kc*4+0]; bb.u[1] = dp[kc*4+1];
            bb.u[2] = dp[kc*4+2]; bb.u[3] = dp[kc*4+3];
            acc0 = __builtin_amdgcn_mfma_f32_16x16x32_bf16(afrag[0][kc].v, bb.v, acc0, 0, 0, 0);
            acc1 = __builtin_amdgcn_mfma_f32_16x16x32_bf16(afrag[1][kc].v, bb.v, acc1, 0, 0, 0);
        }
        if (mymask[t]) {   // output col = fr = my loaded doc row
            #pragma unroll
            for (int r = 0; r < 4; ++r) {
                rmax[0][r] = fmaxf(rmax[0][r], acc0[r] * rnd);
                rmax[1][r] = fmaxf(rmax[1][r], acc1[r] * rnd);
            }
        }
    };

    // software pipeline: loads for tile t+1 in flight during tile t MFMAs
    loadpack(0, dpa, rnda);
    loadpack(1, dpb, rndb);
    dotile(0, dpa, rnda);
    loadpack(2, dpa, rnda);
    dotile(1, dpb, rndb);
    loadpack(3, dpb, rndb);
    dotile(2, dpa, rnda);
    dotile(3, dpb, rndb);

    // ---- reduce max over the wave's 16 doc columns (lanes within fp-group) ----
    #pragma unroll
    for (int qh = 0; qh < 2; ++qh)
        #pragma unroll
        for (int r = 0; r < 4; ++r) {
            float m = rmax[qh][r];
            m = fmaxf(m, __shfl_xor(m, 1));
            m = fmaxf(m, __shfl_xor(m, 2));
            m = fmaxf(m, __shfl_xor(m, 4));
            m = fmaxf(m, __shfl_xor(m, 8));
            rmax[qh][r] = m;
        }
    if (fr == 0) {
        #pragma unroll
        for (int qh = 0; qh < 2; ++qh)
            #pragma unroll
            for (int r = 0; r < 4; ++r)
                qmaxw[w][qh * 16 + fp * 4 + r] = rmax[qh][r];
    }
    __syncthreads();

    // ---- combine 4 waves, sum over q, publish score, completion count ----
    if (w == 0) {
        float s = 0.f;
        if (lane < 32) {
            s = fmaxf(fmaxf(qmaxw[0][lane], qmaxw[1][lane]),
                      fmaxf(qmaxw[2][lane], qmaxw[3][lane]));
        }
        s += __shfl_xor(s, 1);  s += __shfl_xor(s, 2);  s += __shfl_xor(s, 4);
        s += __shfl_xor(s, 8);  s += __shfl_xor(s, 16); s += __shfl_xor(s, 32);
        if (lane == 0) {
            __hip_atomic_store(&scores[bn], s, __ATOMIC_RELEASE, __HIP_MEMORY_SCOPE_AGENT);
            unsigned old = __hip_atomic_fetch_add(cnt, 1u, __ATOMIC_ACQ_REL, __HIP_MEMORY_SCOPE_AGENT);
            islast = (old == NBLOCKS - 1) ? 1u : 0u;
        }
    }
    __syncthreads();

    // ---- last block computes the loss (all 512 scores released) ----
    if (islast && tid < 64) {
        const int bb = tid;
        float sc[NWAY];
        float m = -1e30f;
        #pragma unroll
        for (int j = 0; j < NWAY; ++j) {
            sc[j] = __hip_atomic_load(&scores[bb * NWAY + j],
                                      __ATOMIC_ACQUIRE, __HIP_MEMORY_SCOPE_AGENT);
            m = fmaxf(m, sc[j]);
        }
        float se = 0.f;
        #pragma unroll
        for (int j = 0; j < NWAY; ++j) se += expf(sc[j] - m);
        const float lse = m + logf(se);

        float lossb = 0.f, posb = 0.f;
        #pragma unroll
        for (int j = 0; j < NWAY; ++j) {
            const float ls = sc[j] - lse;
            const float tg = labels[bb * 2 * NWAY + j];
            const float wv = labels[bb * 2 * NWAY + NWAY + j];
            lossb += expf(tg) * (tg - ls);
            posb  += ls * wv;
        }
        float a = lossb, p = posb;
        #pragma unroll
        for (int d = 1; d < 64; d <<= 1) { a += __shfl_xor(a, d); p += __shfl_xor(p, d); }
        if (tid == 0) out[0] = a / 512.0f - 0.1f * p;
    }
}

extern "C" void kernel_launch(void* const* d_in, const int* in_sizes, int n_in,
                              void* d_out, int out_size, void* d_ws, size_t ws_size,
                              hipStream_t stream) {
    const float* qreps  = (const float*)d_in[0];
    const float* dreps  = (const float*)d_in[1];
    const int*   masks  = (const int*)d_in[2];
    const float* labels = (const float*)d_in[3];
    float*    scores = (float*)d_ws;                                   // 512 floats
    unsigned* cnt    = (unsigned*)((char*)d_ws + NBLOCKS * sizeof(float));
    float*    out    = (float*)d_out;

    hipMemsetAsync(cnt, 0, sizeof(unsigned), stream);   // counter must start at 0
    colbert_fused_kernel<<<NBLOCKS, 256, 0, stream>>>(qreps, dreps, masks, labels,
                                                      scores, cnt, out);
}

// Round 6
// 31.726 us; speedup vs baseline: 1.1789x; 1.1789x over previous
//
#include <hip/hip_runtime.h>
#include <hip/hip_bf16.h>

#define NB 64
#define LQ 32
#define LD 256
#define DD 128
#define NWAY 8
#define KT 64            // doc rows per tile; 4 tiles
#define NBLOCKS (NB * NWAY)   // 512
#define LDSROW 136       // 128 + 8 bf16 pad -> 272B row stride, 16B aligned

typedef __attribute__((ext_vector_type(8))) short short8;
typedef __attribute__((ext_vector_type(4))) float f32x4;

static __device__ __forceinline__ unsigned short f2bf(float f) {
    unsigned int u = __float_as_uint(f);
    u += 0x7fffu + ((u >> 16) & 1u);   // round-to-nearest-even
    return (unsigned short)(u >> 16);
}
static __device__ __forceinline__ unsigned int pk2(float a, float b) {
    return (unsigned int)f2bf(a) | ((unsigned int)f2bf(b) << 16);
}

// One block per (b,n), 512 threads = 8 waves (wave = kq*2+qh).
// b=bid&63, n=bid>>6: the 8 blocks sharing b land on one XCD -> Q reads L2-hit.
// Doc rows: masked rows never loaded (gated on REGISTER masks loaded at cycle 0);
// stored unnormalized bf16, 1/||d|| applied post-MFMA (max commutes with
// positive scales). Loss fused into the last-arriving block via atomic counter.
__global__ __launch_bounds__(512, 4) void colbert_fused_kernel(
    const float* __restrict__ qreps,   // [B][LQ][DD]
    const float* __restrict__ dreps,   // [B][NWAY][LD][DD]
    const int*   __restrict__ masks,   // [B][NWAY][LD]
    const float* __restrict__ labels,  // [B][2*NWAY]
    float*       __restrict__ scores,  // ws: [512]
    unsigned*    __restrict__ cnt,     // ws: completion counter (memset 0 per call)
    float*       __restrict__ out)
{
    const int bid  = blockIdx.x;
    const int b    = bid & 63;
    const int n    = bid >> 6;
    const int bn   = b * NWAY + n;
    const int tid  = threadIdx.x;
    const int lane = tid & 63;
    const int w    = tid >> 6;

    __shared__ __align__(16) unsigned short qs[LQ * LDSROW];       // normalized q bf16
    __shared__ __align__(16) unsigned short dsb[2][KT * LDSROW];   // raw doc bf16, dbuf
    __shared__ float rnds[2][KT];
    __shared__ int   mks[LD];
    __shared__ float qmaxs[4][LQ];
    __shared__ unsigned islast;

    const int row = tid >> 3;          // doc row within tile (0..63)
    const int seg = tid & 7;           // 16-float segment

    // ---- cycle 0: my row's masks for all 4 tiles -> registers ----
    int mymask[4];
    #pragma unroll
    for (int t = 0; t < 4; ++t)
        mymask[t] = masks[(size_t)bn * LD + t * KT + row];

    // ---- concurrent: waves 4-7 load LDS masks; waves 0-3 load+normalize Q ----
    if (tid >= 256) {
        const int i = tid - 256;
        mks[i] = masks[(size_t)bn * LD + i];
    } else {
        const int qrow = tid >> 3, qseg = tid & 7;
        const float* src = qreps + ((size_t)b * LQ + qrow) * DD + qseg * 16;
        float4 q0 = reinterpret_cast<const float4*>(src)[0];
        float4 q1 = reinterpret_cast<const float4*>(src)[1];
        float4 q2 = reinterpret_cast<const float4*>(src)[2];
        float4 q3 = reinterpret_cast<const float4*>(src)[3];
        float ss = q0.x*q0.x + q0.y*q0.y + q0.z*q0.z + q0.w*q0.w
                 + q1.x*q1.x + q1.y*q1.y + q1.z*q1.z + q1.w*q1.w
                 + q2.x*q2.x + q2.y*q2.y + q2.z*q2.z + q2.w*q2.w
                 + q3.x*q3.x + q3.y*q3.y + q3.z*q3.z + q3.w*q3.w;
        ss += __shfl_xor(ss, 1); ss += __shfl_xor(ss, 2); ss += __shfl_xor(ss, 4);
        const float rn = rsqrtf(fmaxf(ss, 1e-24f));
        unsigned int qp[8] = {
            pk2(q0.x*rn, q0.y*rn), pk2(q0.z*rn, q0.w*rn),
            pk2(q1.x*rn, q1.y*rn), pk2(q1.z*rn, q1.w*rn),
            pk2(q2.x*rn, q2.y*rn), pk2(q2.z*rn, q2.w*rn),
            pk2(q3.x*rn, q3.y*rn), pk2(q3.z*rn, q3.w*rn) };
        unsigned short* dst = &qs[qrow * LDSROW + qseg * 16];
        reinterpret_cast<uint4*>(dst)[0] = *reinterpret_cast<const uint4*>(&qp[0]);
        reinterpret_cast<uint4*>(dst)[1] = *reinterpret_cast<const uint4*>(&qp[4]);
    }

    float va[16], vb[16];

    // gated on REGISTER mask -> doc loads issue without any barrier dependency
    auto prefetch = [&](float (&v)[16], int t) {
        if (mymask[t]) {
            const float* src = dreps + ((size_t)bn * LD + t * KT + row) * DD + seg * 16;
            #pragma unroll
            for (int i = 0; i < 4; ++i) {
                float4 f = reinterpret_cast<const float4*>(src)[i];
                v[4*i] = f.x; v[4*i+1] = f.y; v[4*i+2] = f.z; v[4*i+3] = f.w;
            }
        }
    };
    // pack-only staging; rnds = deferred per-row scale.
    // mymask uniform across the row's 8 lanes -> shfl convergent within group.
    auto stagewrite = [&](float (&v)[16], int t, int bf) {
        if (mymask[t]) {
            unsigned int dp[8];
            #pragma unroll
            for (int i = 0; i < 8; ++i) dp[i] = pk2(v[2*i], v[2*i+1]);
            unsigned short* dst = &dsb[bf][row * LDSROW + seg * 16];
            reinterpret_cast<uint4*>(dst)[0] = *reinterpret_cast<const uint4*>(&dp[0]);
            reinterpret_cast<uint4*>(dst)[1] = *reinterpret_cast<const uint4*>(&dp[4]);
            float ss = 0.f;
            #pragma unroll
            for (int i = 0; i < 16; ++i) ss += v[i] * v[i];
            ss += __shfl_xor(ss, 1); ss += __shfl_xor(ss, 2); ss += __shfl_xor(ss, 4);
            if (seg == 0) rnds[bf][row] = rsqrtf(fmaxf(ss, 1e-24f));
        }
    };

    const int frow  = lane & 15;
    const int fpack = lane >> 4;
    const int qh    = w & 1;
    const int kq    = w >> 1;
    const unsigned short* aptr = &qs[(qh * 16 + frow) * LDSROW + fpack * 8];

    float rmax[4] = {-1e30f, -1e30f, -1e30f, -1e30f};

    auto mfma_max = [&](int t, int bf) {
        const int drow = kq * 16 + frow;   // doc row within tile -> output column
        const unsigned short* bptr = &dsb[bf][drow * LDSROW + fpack * 8];
        f32x4 acc = {0.f, 0.f, 0.f, 0.f};
        #pragma unroll
        for (int kc = 0; kc < 4; ++kc) {
            short8 a  = *reinterpret_cast<const short8*>(aptr + kc * 32);
            short8 bb = *reinterpret_cast<const short8*>(bptr + kc * 32);
            acc = __builtin_amdgcn_mfma_f32_16x16x32_bf16(a, bb, acc, 0, 0, 0);
        }
        if (mks[t * KT + drow]) {
            const float rnd = rnds[bf][drow];
            #pragma unroll
            for (int r = 0; r < 4; ++r) rmax[r] = fmaxf(rmax[r], acc[r] * rnd);
        }
    };

    // ---- 4-tile pipeline, 2 LDS buffers, distance-2 register prefetch ----
    prefetch(va, 0);  prefetch(vb, 1);
    stagewrite(va, 0, 0);
    __syncthreads();               // dsb[0] (t0), qs, mks ready
    prefetch(va, 2);
    mfma_max(0, 0);                // read dsb[0]
    stagewrite(vb, 1, 1);          // write dsb[1]
    __syncthreads();               // dsb[1] (t1) ready, dsb[0] free
    prefetch(vb, 3);
    mfma_max(1, 1);
    stagewrite(va, 2, 0);
    __syncthreads();
    mfma_max(2, 0);
    stagewrite(vb, 3, 1);
    __syncthreads();
    mfma_max(3, 1);

    // ---- reduce max over 16 doc-columns within wave ----
    #pragma unroll
    for (int r = 0; r < 4; ++r) {
        float m = rmax[r];
        m = fmaxf(m, __shfl_xor(m, 1));
        m = fmaxf(m, __shfl_xor(m, 2));
        m = fmaxf(m, __shfl_xor(m, 4));
        m = fmaxf(m, __shfl_xor(m, 8));
        rmax[r] = m;
    }
    if ((lane & 15) == 0) {
        const int qr = qh * 16 + fpack * 4;
        #pragma unroll
        for (int r = 0; r < 4; ++r) qmaxs[kq][qr + r] = rmax[r];
    }
    __syncthreads();

    // ---- combine k-quarters, sum over q, publish score + completion count ----
    if (w == 0) {
        float s = 0.f;
        if (lane < 32)
            s = fmaxf(fmaxf(qmaxs[0][lane], qmaxs[1][lane]),
                      fmaxf(qmaxs[2][lane], qmaxs[3][lane]));
        s += __shfl_xor(s, 1);  s += __shfl_xor(s, 2);  s += __shfl_xor(s, 4);
        s += __shfl_xor(s, 8);  s += __shfl_xor(s, 16); s += __shfl_xor(s, 32);
        if (lane == 0) {
            __hip_atomic_store(&scores[bn], s, __ATOMIC_RELEASE, __HIP_MEMORY_SCOPE_AGENT);
            unsigned old = __hip_atomic_fetch_add(cnt, 1u, __ATOMIC_ACQ_REL,
                                                  __HIP_MEMORY_SCOPE_AGENT);
            islast = (old == NBLOCKS - 1) ? 1u : 0u;
        }
    }
    __syncthreads();

    // ---- last block computes the loss (all 512 scores released) ----
    if (islast && tid < 64) {
        const int bb = tid;
        float sc[NWAY];
        float m = -1e30f;
        #pragma unroll
        for (int j = 0; j < NWAY; ++j) {
            sc[j] = __hip_atomic_load(&scores[bb * NWAY + j],
                                      __ATOMIC_ACQUIRE, __HIP_MEMORY_SCOPE_AGENT);
            m = fmaxf(m, sc[j]);
        }
        float se = 0.f;
        #pragma unroll
        for (int j = 0; j < NWAY; ++j) se += expf(sc[j] - m);
        const float lse = m + logf(se);

        float lossb = 0.f, posb = 0.f;
        #pragma unroll
        for (int j = 0; j < NWAY; ++j) {
            const float ls = sc[j] - lse;
            const float tg = labels[bb * 2 * NWAY + j];
            const float wv = labels[bb * 2 * NWAY + NWAY + j];
            lossb += expf(tg) * (tg - ls);
            posb  += ls * wv;
        }
        float a = lossb, p = posb;
        #pragma unroll
        for (int d = 1; d < 64; d <<= 1) { a += __shfl_xor(a, d); p += __shfl_xor(p, d); }
        if (tid == 0) out[0] = a / 512.0f - 0.1f * p;
    }
}

extern "C" void kernel_launch(void* const* d_in, const int* in_sizes, int n_in,
                              void* d_out, int out_size, void* d_ws, size_t ws_size,
                              hipStream_t stream) {
    const float* qreps  = (const float*)d_in[0];
    const float* dreps  = (const float*)d_in[1];
    const int*   masks  = (const int*)d_in[2];
    const float* labels = (const float*)d_in[3];
    float*    scores = (float*)d_ws;                                   // 512 floats
    unsigned* cnt    = (unsigned*)((char*)d_ws + NBLOCKS * sizeof(float));
    float*    out    = (float*)d_out;

    hipMemsetAsync(cnt, 0, sizeof(unsigned), stream);   // counter must start at 0
    colbert_fused_kernel<<<NBLOCKS, 512, 0, stream>>>(qreps, dreps, masks, labels,
                                                      scores, cnt, out);
}

// Round 7
// 25.695 us; speedup vs baseline: 1.4556x; 1.2347x over previous
//
#include <hip/hip_runtime.h>
#include <hip/hip_bf16.h>

#define NB 64
#define LQ 32
#define LD 256
#define DD 128
#define NWAY 8
#define KT 32                 // doc rows per tile; 2 tiles per block
#define NBLK (NB * NWAY * 4)  // 2048 blocks: one per (b,n,quarter)
#define LDSROW 136            // 128 + 8 bf16 pad -> 272B stride (2-way alias, free)

typedef __attribute__((ext_vector_type(8))) short short8;
typedef __attribute__((ext_vector_type(4))) float f32x4;

static __device__ __forceinline__ unsigned short f2bf(float f) {
    unsigned int u = __float_as_uint(f);
    u += 0x7fffu + ((u >> 16) & 1u);   // round-to-nearest-even
    return (unsigned short)(u >> 16);
}
static __device__ __forceinline__ unsigned int pk2(float a, float b) {
    return (unsigned int)f2bf(a) | ((unsigned int)f2bf(b) << 16);
}

// Block bid: b = bid&63, r = bid>>6, n = r&7, qt = r>>3.
// All 32 blocks of one b differ by multiples of 64 (== 0 mod 8) -> same XCD,
// so Q/mask re-reads are XCD-L2 hits; doc reads are unique (masked rows skipped).
// 256 threads = 4 waves: wave = (kq<<1)|qh. Each block: 64 doc rows, 2 tiles
// of 32, double-buffered LDS; doc rows stored UNNORMALIZED bf16, 1/||d||
// applied post-MFMA (max commutes with positive scales). LDS ~26.6KB ->
// 6 blocks/CU = 24 waves/CU.
__global__ __launch_bounds__(256, 6) void colbert_part_kernel(
    const float* __restrict__ qreps,   // [B][LQ][DD]
    const float* __restrict__ dreps,   // [B][NWAY][LD][DD]
    const int*   __restrict__ masks,   // [B][NWAY][LD]
    float*       __restrict__ qpart)   // [512*4][LQ] per-q partial max
{
    const int bid  = blockIdx.x;
    const int b    = bid & 63;
    const int r_   = bid >> 6;
    const int n    = r_ & 7;
    const int qt   = r_ >> 3;
    const int bn   = b * NWAY + n;
    const int tid  = threadIdx.x;
    const int lane = tid & 63;
    const int w    = tid >> 6;         // 0..3

    __shared__ __align__(16) unsigned short qs[LQ * LDSROW];       // normalized q bf16
    __shared__ __align__(16) unsigned short dsb[2][KT * LDSROW];   // raw doc bf16, dbuf
    __shared__ float rnds[2][KT];
    __shared__ float qmaxs[2][LQ];

    const int row = tid >> 3;          // doc row within tile (0..31)
    const int seg = tid & 7;           // 16-float segment
    const int frow = lane & 15;
    const int fp   = lane >> 4;
    const int qh   = w & 1;
    const int kq   = w >> 1;

    const size_t mbase = (size_t)bn * LD + qt * 64;

    // ---- cycle 0: register masks (stager rows + mfma columns) ----
    int mymask[2], mmk[2];
    #pragma unroll
    for (int t = 0; t < 2; ++t) {
        mymask[t] = masks[mbase + t * KT + row];
        mmk[t]    = masks[mbase + t * KT + kq * 16 + frow];
    }

    // ---- Q load + normalize -> LDS (32 rows x 8 threads/row), L2-served ----
    {
        const float* src = qreps + ((size_t)b * LQ + row) * DD + seg * 16;
        float4 q0 = reinterpret_cast<const float4*>(src)[0];
        float4 q1 = reinterpret_cast<const float4*>(src)[1];
        float4 q2 = reinterpret_cast<const float4*>(src)[2];
        float4 q3 = reinterpret_cast<const float4*>(src)[3];
        float ss = q0.x*q0.x + q0.y*q0.y + q0.z*q0.z + q0.w*q0.w
                 + q1.x*q1.x + q1.y*q1.y + q1.z*q1.z + q1.w*q1.w
                 + q2.x*q2.x + q2.y*q2.y + q2.z*q2.z + q2.w*q2.w
                 + q3.x*q3.x + q3.y*q3.y + q3.z*q3.z + q3.w*q3.w;
        ss += __shfl_xor(ss, 1); ss += __shfl_xor(ss, 2); ss += __shfl_xor(ss, 4);
        const float rn = rsqrtf(fmaxf(ss, 1e-24f));
        unsigned int qp[8] = {
            pk2(q0.x*rn, q0.y*rn), pk2(q0.z*rn, q0.w*rn),
            pk2(q1.x*rn, q1.y*rn), pk2(q1.z*rn, q1.w*rn),
            pk2(q2.x*rn, q2.y*rn), pk2(q2.z*rn, q2.w*rn),
            pk2(q3.x*rn, q3.y*rn), pk2(q3.z*rn, q3.w*rn) };
        unsigned short* dst = &qs[row * LDSROW + seg * 16];
        reinterpret_cast<uint4*>(dst)[0] = *reinterpret_cast<const uint4*>(&qp[0]);
        reinterpret_cast<uint4*>(dst)[1] = *reinterpret_cast<const uint4*>(&qp[4]);
    }

    float va[16], vb[16];

    auto prefetch = [&](float (&v)[16], int t) {
        if (mymask[t]) {
            const float* src = dreps + (mbase + t * KT + row) * DD + seg * 16;
            #pragma unroll
            for (int i = 0; i < 4; ++i) {
                float4 f = reinterpret_cast<const float4*>(src)[i];
                v[4*i] = f.x; v[4*i+1] = f.y; v[4*i+2] = f.z; v[4*i+3] = f.w;
            }
        }
    };
    // pack-only staging; mymask uniform across the row's 8 lanes -> shfl safe
    auto stagewrite = [&](float (&v)[16], int t, int bf) {
        if (mymask[t]) {
            unsigned int dp[8];
            #pragma unroll
            for (int i = 0; i < 8; ++i) dp[i] = pk2(v[2*i], v[2*i+1]);
            unsigned short* dst = &dsb[bf][row * LDSROW + seg * 16];
            reinterpret_cast<uint4*>(dst)[0] = *reinterpret_cast<const uint4*>(&dp[0]);
            reinterpret_cast<uint4*>(dst)[1] = *reinterpret_cast<const uint4*>(&dp[4]);
            float ss = 0.f;
            #pragma unroll
            for (int i = 0; i < 16; ++i) ss += v[i] * v[i];
            ss += __shfl_xor(ss, 1); ss += __shfl_xor(ss, 2); ss += __shfl_xor(ss, 4);
            if (seg == 0) rnds[bf][row] = rsqrtf(fmaxf(ss, 1e-24f));
        }
    };

    const unsigned short* aptr = &qs[(qh * 16 + frow) * LDSROW + fp * 8];
    float rmax[4] = {-1e30f, -1e30f, -1e30f, -1e30f};

    auto mfma_max = [&](int t, int bf) {
        const int drow = kq * 16 + frow;   // doc row in tile -> output column
        const unsigned short* bptr = &dsb[bf][drow * LDSROW + fp * 8];
        f32x4 acc = {0.f, 0.f, 0.f, 0.f};
        #pragma unroll
        for (int kc = 0; kc < 4; ++kc) {
            short8 a  = *reinterpret_cast<const short8*>(aptr + kc * 32);
            short8 bb = *reinterpret_cast<const short8*>(bptr + kc * 32);
            acc = __builtin_amdgcn_mfma_f32_16x16x32_bf16(a, bb, acc, 0, 0, 0);
        }
        if (mmk[t]) {
            const float rnd = rnds[bf][drow];
            #pragma unroll
            for (int rr = 0; rr < 4; ++rr) rmax[rr] = fmaxf(rmax[rr], acc[rr] * rnd);
        }
    };

    // ---- 2-tile pipeline ----
    prefetch(va, 0);  prefetch(vb, 1);
    stagewrite(va, 0, 0);
    __syncthreads();               // dsb[0], qs ready
    mfma_max(0, 0);
    stagewrite(vb, 1, 1);
    __syncthreads();               // dsb[1] ready
    mfma_max(1, 1);

    // ---- reduce max over 16 doc-columns within wave ----
    #pragma unroll
    for (int rr = 0; rr < 4; ++rr) {
        float m = rmax[rr];
        m = fmaxf(m, __shfl_xor(m, 1));
        m = fmaxf(m, __shfl_xor(m, 2));
        m = fmaxf(m, __shfl_xor(m, 4));
        m = fmaxf(m, __shfl_xor(m, 8));
        rmax[rr] = m;
    }
    if (frow == 0) {
        const int qr = qh * 16 + fp * 4;
        #pragma unroll
        for (int rr = 0; rr < 4; ++rr) qmaxs[kq][qr + rr] = rmax[rr];
    }
    __syncthreads();

    // ---- per-q partial max for this quarter -> ws ----
    if (w == 0 && lane < 32)
        qpart[((size_t)bn * 4 + qt) * LQ + lane] = fmaxf(qmaxs[0][lane], qmaxs[1][lane]);
}

// One block, 512 threads: thread bn combines 4 quarters, then softmax + KL.
__global__ __launch_bounds__(512) void colbert_loss_kernel(
    const float* __restrict__ qpart,    // [512*4][LQ]
    const float* __restrict__ labels,   // [B][2*NWAY]
    float*       __restrict__ out)
{
    const int bn = threadIdx.x;         // 0..511
    const int b  = bn >> 3;
    const int n  = bn & 7;

    float vmax[LQ];
    const float* src = qpart + (size_t)bn * 4 * LQ;
    #pragma unroll
    for (int i = 0; i < 8; ++i) {
        float4 f = reinterpret_cast<const float4*>(src)[i];
        vmax[4*i] = f.x; vmax[4*i+1] = f.y; vmax[4*i+2] = f.z; vmax[4*i+3] = f.w;
    }
    #pragma unroll
    for (int h = 1; h < 4; ++h) {
        #pragma unroll
        for (int i = 0; i < 8; ++i) {
            float4 f = reinterpret_cast<const float4*>(src + h * LQ)[i];
            vmax[4*i]   = fmaxf(vmax[4*i],   f.x);
            vmax[4*i+1] = fmaxf(vmax[4*i+1], f.y);
            vmax[4*i+2] = fmaxf(vmax[4*i+2], f.z);
            vmax[4*i+3] = fmaxf(vmax[4*i+3], f.w);
        }
    }
    float score = 0.f;
    #pragma unroll
    for (int q = 0; q < LQ; ++q) score += vmax[q];

    // softmax over the 8 n's (consecutive lanes within the wave)
    float m = score;
    m = fmaxf(m, __shfl_xor(m, 1)); m = fmaxf(m, __shfl_xor(m, 2)); m = fmaxf(m, __shfl_xor(m, 4));
    float e = expf(score - m);
    float se = e;
    se += __shfl_xor(se, 1); se += __shfl_xor(se, 2); se += __shfl_xor(se, 4);
    const float lse = m + logf(se);
    const float ls  = score - lse;

    const float tg = labels[b * 2 * NWAY + n];
    const float wv = labels[b * 2 * NWAY + NWAY + n];
    float aterm = expf(tg) * (tg - ls);
    float pterm = ls * wv;

    #pragma unroll
    for (int d = 1; d < 64; d <<= 1) {
        aterm += __shfl_xor(aterm, d);
        pterm += __shfl_xor(pterm, d);
    }
    __shared__ float wa[8], wp[8];
    const int wv_id = threadIdx.x >> 6;
    if ((threadIdx.x & 63) == 0) { wa[wv_id] = aterm; wp[wv_id] = pterm; }
    __syncthreads();
    if (threadIdx.x == 0) {
        float A = 0.f, P = 0.f;
        #pragma unroll
        for (int i = 0; i < 8; ++i) { A += wa[i]; P += wp[i]; }
        out[0] = A / 512.0f - 0.1f * P;
    }
}

extern "C" void kernel_launch(void* const* d_in, const int* in_sizes, int n_in,
                              void* d_out, int out_size, void* d_ws, size_t ws_size,
                              hipStream_t stream) {
    const float* qreps  = (const float*)d_in[0];
    const float* dreps  = (const float*)d_in[1];
    const int*   masks  = (const int*)d_in[2];
    const float* labels = (const float*)d_in[3];
    float* qpart = (float*)d_ws;             // 2048*32 floats = 256 KB
    float* out   = (float*)d_out;

    colbert_part_kernel<<<NBLK, 256, 0, stream>>>(qreps, dreps, masks, qpart);
    colbert_loss_kernel<<<1, 512, 0, stream>>>(qpart, labels, out);
}

// Round 8
// 16.270 us; speedup vs baseline: 2.2987x; 1.5793x over previous
//
#include <hip/hip_runtime.h>
#include <hip/hip_bf16.h>

#define NB 64
#define LQ 32
#define LD 256
#define DD 128
#define NWAY 8
#define NBLOCKS (NB * NWAY)   // 512
#define DSROW 136             // shorts per doc/q row: 128 data + 8 pad (272B stride)
// dynamic LDS layout: ds[256][136] + qs[32][136] + rnds[256] + qmaxs[4][32]
#define SMEM_BYTES ((256 + 32) * DSROW * 2 + 256 * 4 + 128 * 4)   // 79872

typedef __attribute__((ext_vector_type(8))) short short8;
typedef __attribute__((ext_vector_type(4))) float f32x4;

static __device__ __forceinline__ unsigned short f2bf(float f) {
    unsigned int u = __float_as_uint(f);
    u += 0x7fffu + ((u >> 16) & 1u);   // round-to-nearest-even
    return (unsigned short)(u >> 16);
}
static __device__ __forceinline__ unsigned int pk2(float a, float b) {
    return (unsigned int)f2bf(a) | ((unsigned int)f2bf(b) << 16);
}

// One block per (b,n): b=bid&63, n=bid>>6 (same-b blocks -> same XCD L2 for Q).
// 512 threads = 8 waves (wave = kq*2+qh). SINGLE-PHASE structure:
//   issue ALL gated global loads -> pack bf16 -> LDS -> ONE barrier -> MFMA.
// Exactly one vmcnt drain per block => memory queue stays full (Little's law).
// Doc rows unnormalized bf16; 1/||d|| applied post-MFMA (max commutes with
// positive scales). Masked rows never loaded; garbage LDS/NaN only reaches
// gated-out columns.
__global__ __launch_bounds__(512, 4) void colbert_scores_kernel(
    const float* __restrict__ qreps,   // [B][LQ][DD]
    const float* __restrict__ dreps,   // [B][NWAY][LD][DD]
    const int*   __restrict__ masks,   // [B][NWAY][LD]
    float*       __restrict__ scores)  // [512]
{
    extern __shared__ unsigned short smem[];
    unsigned short* ds_  = smem;                          // [256][DSROW]
    unsigned short* qs   = smem + 256 * DSROW;            // [32][DSROW]
    float*          rnds = (float*)(smem + (256 + 32) * DSROW);   // [256]
    float*          qmaxs = rnds + 256;                   // [4][32]

    const int bid  = blockIdx.x;
    const int b    = bid & 63;
    const int n    = bid >> 6;
    const int bn   = b * NWAY + n;
    const int tid  = threadIdx.x;
    const int lane = tid & 63;
    const int w    = tid >> 6;         // 0..7
    const int fr   = lane & 15;
    const int fp   = lane >> 4;
    const int qh   = w & 1;
    const int kq   = w >> 1;           // 0..3

    const int row  = tid >> 1;         // doc row 0..255
    const int half = tid & 1;          // which 64-float half of the row

    // ---- entry: all masks to registers (gate loads; no LDS round-trip) ----
    const int rm = masks[(size_t)bn * LD + row];
    int cm[4];
    #pragma unroll
    for (int tt = 0; tt < 4; ++tt)
        cm[tt] = masks[(size_t)bn * LD + tt * 64 + kq * 16 + fr];

    // ---- issue ALL doc loads (gated), 16x float4 per thread ----
    float4 fa[8], fb[8];
    const float* dsrc = dreps + ((size_t)bn * LD + row) * DD + half * 64;
    if (rm) {
        #pragma unroll
        for (int i = 0; i < 8; ++i) fa[i] = reinterpret_cast<const float4*>(dsrc)[i];
        #pragma unroll
        for (int i = 0; i < 8; ++i) fb[i] = reinterpret_cast<const float4*>(dsrc + 32)[i];
    }

    // ---- Q: load + normalize + pack -> LDS (threads 0..255; 8 threads/row) ----
    if (tid < 256) {
        const int qrow = tid >> 3, qseg = tid & 7;
        const float* src = qreps + ((size_t)b * LQ + qrow) * DD + qseg * 16;
        float4 q0 = reinterpret_cast<const float4*>(src)[0];
        float4 q1 = reinterpret_cast<const float4*>(src)[1];
        float4 q2 = reinterpret_cast<const float4*>(src)[2];
        float4 q3 = reinterpret_cast<const float4*>(src)[3];
        float ss = q0.x*q0.x + q0.y*q0.y + q0.z*q0.z + q0.w*q0.w
                 + q1.x*q1.x + q1.y*q1.y + q1.z*q1.z + q1.w*q1.w
                 + q2.x*q2.x + q2.y*q2.y + q2.z*q2.z + q2.w*q2.w
                 + q3.x*q3.x + q3.y*q3.y + q3.z*q3.z + q3.w*q3.w;
        ss += __shfl_xor(ss, 1); ss += __shfl_xor(ss, 2); ss += __shfl_xor(ss, 4);
        const float rn = rsqrtf(fmaxf(ss, 1e-24f));
        unsigned int qp[8] = {
            pk2(q0.x*rn, q0.y*rn), pk2(q0.z*rn, q0.w*rn),
            pk2(q1.x*rn, q1.y*rn), pk2(q1.z*rn, q1.w*rn),
            pk2(q2.x*rn, q2.y*rn), pk2(q2.z*rn, q2.w*rn),
            pk2(q3.x*rn, q3.y*rn), pk2(q3.z*rn, q3.w*rn) };
        unsigned short* dst = &qs[qrow * DSROW + qseg * 16];
        reinterpret_cast<uint4*>(dst)[0] = *reinterpret_cast<const uint4*>(&qp[0]);
        reinterpret_cast<uint4*>(dst)[1] = *reinterpret_cast<const uint4*>(&qp[4]);
    }

    // ---- doc: ssq + pack raw bf16 -> LDS; rnds = 1/||row|| ----
    if (rm) {   // rm uniform across the 2 lanes of a row -> shfl convergent
        float ss = 0.f;
        #pragma unroll
        for (int i = 0; i < 8; ++i)
            ss += fa[i].x*fa[i].x + fa[i].y*fa[i].y + fa[i].z*fa[i].z + fa[i].w*fa[i].w
                + fb[i].x*fb[i].x + fb[i].y*fb[i].y + fb[i].z*fb[i].z + fb[i].w*fb[i].w;
        ss += __shfl_xor(ss, 1);        // partner = other half of same row
        const float rn = rsqrtf(fmaxf(ss, 1e-24f));
        if (half == 0) rnds[row] = rn;

        unsigned short* dst = &ds_[row * DSROW + half * 64];
        #pragma unroll
        for (int i = 0; i < 8; ++i) {
            unsigned int dp[4] = { pk2(fa[i].x, fa[i].y), pk2(fa[i].z, fa[i].w),
                                   0u, 0u };
            // overwrite dp[2..3] with fb pair to emit 8x uint4 total (a then b)
            dp[2] = 0u; dp[3] = 0u;
            (void)dp;
            break;   // (placeholder removed below)
        }
        // pack fa -> 4 uint4 (floats 0..31), fb -> 4 uint4 (floats 32..63)
        #pragma unroll
        for (int i = 0; i < 4; ++i) {
            unsigned int dp[4] = {
                pk2(fa[2*i].x, fa[2*i].y),   pk2(fa[2*i].z, fa[2*i].w),
                pk2(fa[2*i+1].x, fa[2*i+1].y), pk2(fa[2*i+1].z, fa[2*i+1].w) };
            reinterpret_cast<uint4*>(dst)[i] = *reinterpret_cast<const uint4*>(dp);
        }
        #pragma unroll
        for (int i = 0; i < 4; ++i) {
            unsigned int dp[4] = {
                pk2(fb[2*i].x, fb[2*i].y),   pk2(fb[2*i].z, fb[2*i].w),
                pk2(fb[2*i+1].x, fb[2*i+1].y), pk2(fb[2*i+1].z, fb[2*i+1].w) };
            reinterpret_cast<uint4*>(dst + 32)[i] = *reinterpret_cast<const uint4*>(dp);
        }
    }

    __syncthreads();   // THE barrier: qs, ds_, rnds all visible

    // ---- hoist A-fragments to registers (read qs once) ----
    short8 afr[4];
    const unsigned short* ap = &qs[(qh * 16 + fr) * DSROW + fp * 8];
    #pragma unroll
    for (int kc = 0; kc < 4; ++kc)
        afr[kc] = *reinterpret_cast<const short8*>(ap + kc * 32);

    // ---- MFMA over 4 column-tiles of 64 (wave covers cols kq*16+fr per tile) ----
    float rmax[4] = {-1e30f, -1e30f, -1e30f, -1e30f};
    #pragma unroll
    for (int tt = 0; tt < 4; ++tt) {
        const int drow = tt * 64 + kq * 16 + fr;
        const unsigned short* bp = &ds_[drow * DSROW + fp * 8];
        f32x4 acc = {0.f, 0.f, 0.f, 0.f};
        #pragma unroll
        for (int kc = 0; kc < 4; ++kc) {
            short8 bb = *reinterpret_cast<const short8*>(bp + kc * 32);
            acc = __builtin_amdgcn_mfma_f32_16x16x32_bf16(afr[kc], bb, acc, 0, 0, 0);
        }
        if (cm[tt]) {
            const float rnd = rnds[drow];
            #pragma unroll
            for (int r = 0; r < 4; ++r) rmax[r] = fmaxf(rmax[r], acc[r] * rnd);
        }
    }

    // ---- reduce max over the 16 doc-columns within each 16-lane group ----
    #pragma unroll
    for (int r = 0; r < 4; ++r) {
        float m = rmax[r];
        m = fmaxf(m, __shfl_xor(m, 1));
        m = fmaxf(m, __shfl_xor(m, 2));
        m = fmaxf(m, __shfl_xor(m, 4));
        m = fmaxf(m, __shfl_xor(m, 8));
        rmax[r] = m;
    }
    if (fr == 0) {
        #pragma unroll
        for (int r = 0; r < 4; ++r)
            qmaxs[kq * 32 + qh * 16 + fp * 4 + r] = rmax[r];
    }
    __syncthreads();

    // ---- combine k-quarters, sum over q rows, store score ----
    if (w == 0) {
        float s = 0.f;
        if (lane < 32)
            s = fmaxf(fmaxf(qmaxs[0 * 32 + lane], qmaxs[1 * 32 + lane]),
                      fmaxf(qmaxs[2 * 32 + lane], qmaxs[3 * 32 + lane]));
        s += __shfl_xor(s, 1);  s += __shfl_xor(s, 2);  s += __shfl_xor(s, 4);
        s += __shfl_xor(s, 8);  s += __shfl_xor(s, 16); s += __shfl_xor(s, 32);
        if (lane == 0) scores[bn] = s;
    }
}

// One wave: thread b handles batch row b.
__global__ __launch_bounds__(64) void colbert_loss_kernel(
    const float* __restrict__ scores,   // [512]
    const float* __restrict__ labels,   // [B][2*NWAY]
    float*       __restrict__ out)
{
    const int b = threadIdx.x;
    float sc[NWAY];
    float m = -1e30f;
    #pragma unroll
    for (int j = 0; j < NWAY; ++j) { sc[j] = scores[b * NWAY + j]; m = fmaxf(m, sc[j]); }
    float se = 0.f;
    #pragma unroll
    for (int j = 0; j < NWAY; ++j) se += expf(sc[j] - m);
    const float lse = m + logf(se);

    float lossb = 0.f, posb = 0.f;
    #pragma unroll
    for (int j = 0; j < NWAY; ++j) {
        const float ls = sc[j] - lse;
        const float tg = labels[b * 2 * NWAY + j];
        const float wv = labels[b * 2 * NWAY + NWAY + j];
        lossb += expf(tg) * (tg - ls);
        posb  += ls * wv;
    }
    float a = lossb, p = posb;
    #pragma unroll
    for (int d = 1; d < 64; d <<= 1) { a += __shfl_xor(a, d); p += __shfl_xor(p, d); }
    if (b == 0) out[0] = a / 512.0f - 0.1f * p;
}

extern "C" void kernel_launch(void* const* d_in, const int* in_sizes, int n_in,
                              void* d_out, int out_size, void* d_ws, size_t ws_size,
                              hipStream_t stream) {
    const float* qreps  = (const float*)d_in[0];
    const float* dreps  = (const float*)d_in[1];
    const int*   masks  = (const int*)d_in[2];
    const float* labels = (const float*)d_in[3];
    float* scoresp = (float*)d_ws;           // 512 floats
    float* out     = (float*)d_out;

    // allow >64KB dynamic LDS (idempotent; non-stream op, capture-safe)
    hipFuncSetAttribute((const void*)colbert_scores_kernel,
                        hipFuncAttributeMaxDynamicSharedMemorySize, SMEM_BYTES);

    colbert_scores_kernel<<<NBLOCKS, 512, SMEM_BYTES, stream>>>(qreps, dreps, masks, scoresp);
    colbert_loss_kernel<<<1, 64, 0, stream>>>(scoresp, labels, out);
}